// Round 6
// baseline (101.592 us; speedup 1.0000x reference)
//
#include <hip/hip_runtime.h>
#include <math.h>

// ContrastiveLoss round 3 (second resubmit after infra failures):
// T-first (register-direct, no LDS) + guarded S path.
// Harness fill of d_ws (~41us) is a fixed floor; this round minimizes our own
// kernel time: t_kernel reads fragments straight from L2, split_E runs only if
// some row is valid (data-dependent, exact), one launch merged away.

constexpr int Bn = 4096;
constexpr int Dd = 512;
constexpr int Ff = 128;

typedef __attribute__((ext_vector_type(8))) short bf16x8;
typedef __attribute__((ext_vector_type(4))) float f32x4;

__device__ __forceinline__ ushort f32_to_bf16(float x) {
    unsigned u = __float_as_uint(x);
    unsigned r = (u + 0x7FFFu + ((u >> 16) & 1u)) >> 16;  // RTNE
    return (ushort)r;
}
__device__ __forceinline__ float bf16_to_f32(ushort h) {
    return __uint_as_float(((unsigned)h) << 16);
}

// prep: L2-normalize + hi/lo split F (1 wave per row), and zero accumulators.
__global__ __launch_bounds__(256) void prep_kernel(const float* __restrict__ sf,
                                                   ushort* __restrict__ fh,
                                                   ushort* __restrict__ fl,
                                                   float* __restrict__ row_sum,
                                                   int* __restrict__ pos_cnt,
                                                   int* __restrict__ rb_any) {
    int gid = blockIdx.x * 256 + threadIdx.x;
    if (gid < Bn) { row_sum[gid] = 0.0f; pos_cnt[gid] = 0; }
    if (gid < Bn / 128 + 1) rb_any[gid] = 0;   // [0..31]=block flags, [32]=any_valid

    int row = blockIdx.x * 4 + (threadIdx.x >> 6);
    int lane = threadIdx.x & 63;
    const float2 v = *reinterpret_cast<const float2*>(&sf[(size_t)row * Ff + lane * 2]);
    float ss = v.x * v.x + v.y * v.y;
    #pragma unroll
    for (int off = 32; off; off >>= 1) ss += __shfl_xor(ss, off, 64);
    float inv = 1.0f / fmaxf(sqrtf(ss), 1e-12f);
    float fx = v.x * inv, fy = v.y * inv;
    ushort hx = f32_to_bf16(fx), hy = f32_to_bf16(fy);
    ushort lx = f32_to_bf16(fx - bf16_to_f32(hx));
    ushort ly = f32_to_bf16(fy - bf16_to_f32(hy));
    ushort2 h; h.x = hx; h.y = hy;
    ushort2 l; l.x = lx; l.y = ly;
    *reinterpret_cast<ushort2*>(&fh[(size_t)row * Ff + lane * 2]) = h;
    *reinterpret_cast<ushort2*>(&fl[(size_t)row * Ff + lane * 2]) = l;
}

// split_E: runs only when some row is valid (any_valid flag). Exact gating:
// row_sum only matters for valid rows, which exist iff any_valid.
__global__ __launch_bounds__(256) void split_E_kernel(const float* __restrict__ E,
                                                      ushort* __restrict__ eh,
                                                      ushort* __restrict__ el,
                                                      const int* __restrict__ rb_any) {
    if (rb_any[Bn / 128] == 0) return;
    size_t i = (size_t)(blockIdx.x * 256 + threadIdx.x) * 4;
    float4 v = *reinterpret_cast<const float4*>(&E[i]);
    float c[4] = {v.x, v.y, v.z, v.w};
    ushort4 h, l;
    ushort hu[4], lu[4];
    #pragma unroll
    for (int j = 0; j < 4; ++j) {
        hu[j] = f32_to_bf16(c[j]);
        lu[j] = f32_to_bf16(c[j] - bf16_to_f32(hu[j]));
    }
    h.x = hu[0]; h.y = hu[1]; h.z = hu[2]; h.w = hu[3];
    l.x = lu[0]; l.y = lu[1]; l.z = lu[2]; l.w = lu[3];
    *reinterpret_cast<ushort4*>(&eh[i]) = h;
    *reinterpret_cast<ushort4*>(&el[i]) = l;
}

__device__ __forceinline__ void tri_decode(int p, int& bi, int& bj) {
    bi = (int)((sqrtf(8.0f * (float)p + 1.0f) - 1.0f) * 0.5f);
    while ((bi + 1) * (bi + 2) / 2 <= p) ++bi;
    while (bi * (bi + 1) / 2 > p) --bi;
    bj = p - bi * (bi + 1) / 2;
}

// T kernel: 128x128 lower-triangle tiles of fn fn^T, fragments loaded straight
// from L2-resident fh/fl (2 MB) into registers. No LDS, no barriers.
__global__ __launch_bounds__(256) void t_kernel(const ushort* __restrict__ Fh,
                                                const ushort* __restrict__ Fl,
                                                unsigned long long* __restrict__ posbits,
                                                int* __restrict__ pos_cnt) {
    int bi, bj; tri_decode(blockIdx.x, bi, bj);
    const int ti = bi * 128, tj = bj * 128;
    const int tid = threadIdx.x;
    const int lane = tid & 63;
    const int wave = tid >> 6;
    const int wrow = (wave >> 1) * 64;
    const int wcol = (wave & 1) * 64;

    f32x4 acc[4][4];
    const f32x4 z4 = {0.0f, 0.0f, 0.0f, 0.0f};
    #pragma unroll
    for (int m = 0; m < 4; ++m)
        #pragma unroll
        for (int n = 0; n < 4; ++n) acc[m][n] = z4;

    const int rA = ti + wrow + (lane & 15);  // A fragment base row
    const int rB = tj + wcol + (lane & 15);  // B fragment base row
    const int kb = (lane >> 4) * 8;          // per-lane K-octet (elements)

    #pragma unroll
    for (int ks = 0; ks < 4; ++ks) {         // K = 4 chunks of 32
        const int ko = ks * 32 + kb;
        bf16x8 ah[4], al[4], bh[4], bl[4];
        #pragma unroll
        for (int m = 0; m < 4; ++m) {
            ah[m] = *reinterpret_cast<const bf16x8*>(&Fh[(size_t)(rA + m * 16) * Ff + ko]);
            al[m] = *reinterpret_cast<const bf16x8*>(&Fl[(size_t)(rA + m * 16) * Ff + ko]);
        }
        #pragma unroll
        for (int n = 0; n < 4; ++n) {
            bh[n] = *reinterpret_cast<const bf16x8*>(&Fh[(size_t)(rB + n * 16) * Ff + ko]);
            bl[n] = *reinterpret_cast<const bf16x8*>(&Fl[(size_t)(rB + n * 16) * Ff + ko]);
        }
        #pragma unroll
        for (int m = 0; m < 4; ++m)
            #pragma unroll
            for (int n = 0; n < 4; ++n) {
                acc[m][n] = __builtin_amdgcn_mfma_f32_16x16x32_bf16(ah[m], bh[n], acc[m][n], 0, 0, 0);
                acc[m][n] = __builtin_amdgcn_mfma_f32_16x16x32_bf16(ah[m], bl[n], acc[m][n], 0, 0, 0);
                acc[m][n] = __builtin_amdgcn_mfma_f32_16x16x32_bf16(al[m], bh[n], acc[m][n], 0, 0, 0);
            }
    }

    // Positive bits (raw T > 0.5); per-tile cache for the S path.
    unsigned long long pm = 0;
    #pragma unroll
    for (int m = 0; m < 4; ++m)
        #pragma unroll
        for (int n = 0; n < 4; ++n)
            #pragma unroll
            for (int r = 0; r < 4; ++r)
                if (acc[m][n][r] > 0.5f) pm |= 1ull << (m * 16 + n * 4 + r);
    posbits[(size_t)blockIdx.x * 256 + tid] = pm;

    // Per-row positive counts (off-diag only), rows + mirrored cols.
    int colC[4] = {0, 0, 0, 0};
    #pragma unroll
    for (int m = 0; m < 4; ++m) {
        #pragma unroll
        for (int r = 0; r < 4; ++r) {
            int c = 0;
            int gi = ti + wrow + m * 16 + ((lane >> 4) << 2) + r;
            #pragma unroll
            for (int n = 0; n < 4; ++n) {
                int gj = tj + wcol + n * 16 + (lane & 15);
                bool pos = (pm >> (m * 16 + n * 4 + r)) & 1;
                if (gi != gj && pos) {
                    c += 1;
                    if (bi != bj) colC[n] += 1;
                }
            }
            #pragma unroll
            for (int off = 8; off; off >>= 1) c += __shfl_xor(c, off, 16);
            if ((lane & 15) == 0 && c) atomicAdd(&pos_cnt[gi], c);
        }
    }
    if (bi != bj) {
        #pragma unroll
        for (int n = 0; n < 4; ++n) {
            int c = colC[n];
            c += __shfl_xor(c, 16, 64);
            c += __shfl_xor(c, 32, 64);
            if ((lane >> 4) == 0 && c) {
                int gj = tj + wcol + n * 16 + (lane & 15);
                atomicAdd(&pos_cnt[gj], c);
            }
        }
    }
}

// valid[i] -> per-128-row-block flags + global any_valid (rb_any[32]).
__global__ __launch_bounds__(256) void flags_kernel(const int* __restrict__ pos_cnt,
                                                    int* __restrict__ rb_any) {
    int i = blockIdx.x * 256 + threadIdx.x;
    int pc = pos_cnt[i];
    if (pc > 0 && pc < Bn - 1) {
        atomicOr(&rb_any[i >> 7], 1);
        atomicOr(&rb_any[Bn / 128], 1);   // any_valid
    }
}

// Stage a 128x64 bf16 tile via global_load_lds w=16; source pre-swizzled
// (rule #21), reads apply same XOR. Validated rounds 1-2: 0 bank conflicts.
__device__ __forceinline__ void stage_tile(const ushort* __restrict__ src, int stride,
                                           int k0, char* tile, int wave, int lane) {
    #pragma unroll
    for (int q = 0; q < 4; ++q) {
        int boff = wave * 4096 + q * 1024 + lane * 16;
        int row = boff >> 7;
        int cb = (boff & 127) ^ ((row & 7) << 4);
        const ushort* g = src + (size_t)row * stride + k0 + (cb >> 1);
        __builtin_amdgcn_global_load_lds(
            (const __attribute__((address_space(1))) void*)g,
            (__attribute__((address_space(3))) void*)(tile + wave * 4096 + q * 1024),
            16, 0, 0);
    }
}

__device__ __forceinline__ void mfma_step(f32x4 (&acc)[4][4], const char* At, const char* Bt,
                                          int wrow, int wcol, int lane) {
    #pragma unroll
    for (int ks = 0; ks < 2; ++ks) {
        bf16x8 a[4], b[4];
        int koff = ks * 64 + ((lane >> 4) << 4);
        #pragma unroll
        for (int m = 0; m < 4; ++m) {
            int row = wrow + m * 16 + (lane & 15);
            a[m] = *reinterpret_cast<const bf16x8*>(At + row * 128 + (koff ^ ((row & 7) << 4)));
        }
        #pragma unroll
        for (int n = 0; n < 4; ++n) {
            int row = wcol + n * 16 + (lane & 15);
            b[n] = *reinterpret_cast<const bf16x8*>(Bt + row * 128 + (koff ^ ((row & 7) << 4)));
        }
        #pragma unroll
        for (int m = 0; m < 4; ++m)
            #pragma unroll
            for (int n = 0; n < 4; ++n)
                acc[m][n] = __builtin_amdgcn_mfma_f32_16x16x32_bf16(a[m], b[n], acc[m][n], 0, 0, 0);
    }
}

// S kernel: exits unless its row/col block contains a valid row.
__global__ __launch_bounds__(256) void s_kernel(const ushort* __restrict__ Eh,
                                                const ushort* __restrict__ El,
                                                const unsigned long long* __restrict__ posbits,
                                                const int* __restrict__ rb_any,
                                                float* __restrict__ row_sum) {
    int bi, bj; tri_decode(blockIdx.x, bi, bj);
    if (!(rb_any[bi] | rb_any[bj])) return;

    __shared__ __align__(16) char smem[65536];
    char* Ah = smem;
    char* Al = smem + 16384;
    char* Bh = smem + 32768;
    char* Bl = smem + 49152;

    const int ti = bi * 128, tj = bj * 128;
    const int tid = threadIdx.x;
    const int lane = tid & 63;
    const int wave = tid >> 6;
    const int wrow = (wave >> 1) * 64;
    const int wcol = (wave & 1) * 64;

    f32x4 acc[4][4];
    const f32x4 z4 = {0.0f, 0.0f, 0.0f, 0.0f};
    #pragma unroll
    for (int m = 0; m < 4; ++m)
        #pragma unroll
        for (int n = 0; n < 4; ++n) acc[m][n] = z4;

    for (int k0 = 0; k0 < Dd; k0 += 64) {
        stage_tile(Eh + (size_t)ti * Dd, Dd, k0, Ah, wave, lane);
        stage_tile(El + (size_t)ti * Dd, Dd, k0, Al, wave, lane);
        stage_tile(Eh + (size_t)tj * Dd, Dd, k0, Bh, wave, lane);
        stage_tile(El + (size_t)tj * Dd, Dd, k0, Bl, wave, lane);
        __syncthreads();
        mfma_step(acc, Ah, Bh, wrow, wcol, lane);
        mfma_step(acc, Ah, Bl, wrow, wcol, lane);
        mfma_step(acc, Al, Bh, wrow, wcol, lane);
        __syncthreads();
    }

    unsigned long long pm = posbits[(size_t)blockIdx.x * 256 + tid];

    float colS[4] = {0, 0, 0, 0};
    #pragma unroll
    for (int m = 0; m < 4; ++m) {
        #pragma unroll
        for (int r = 0; r < 4; ++r) {
            float s = 0.0f;
            int gi = ti + wrow + m * 16 + ((lane >> 4) << 2) + r;
            #pragma unroll
            for (int n = 0; n < 4; ++n) {
                int gj = tj + wcol + n * 16 + (lane & 15);
                if (gi != gj) {
                    float S = acc[m][n][r] * 10.0f;
                    bool pos = (pm >> (m * 16 + n * 4 + r)) & 1;
                    float x = pos ? -S : S;
                    float sp = fmaxf(x, 0.0f) + log1pf(expf(-fabsf(x)));
                    s += sp;
                    if (bi != bj) colS[n] += sp;
                }
            }
            #pragma unroll
            for (int off = 8; off; off >>= 1) s += __shfl_xor(s, off, 16);
            if ((lane & 15) == 0) atomicAdd(&row_sum[gi], s);
        }
    }
    if (bi != bj) {
        #pragma unroll
        for (int n = 0; n < 4; ++n) {
            float s = colS[n];
            s += __shfl_xor(s, 16, 64);
            s += __shfl_xor(s, 32, 64);
            if ((lane >> 4) == 0) {
                int gj = tj + wcol + n * 16 + (lane & 15);
                atomicAdd(&row_sum[gj], s);
            }
        }
    }
}

__global__ __launch_bounds__(256) void finalize_kernel(const float* __restrict__ row_sum,
                                                       const int* __restrict__ pos_cnt,
                                                       float* __restrict__ out) {
    __shared__ float ssum[256];
    __shared__ int scnt[256];
    float ls = 0.0f;
    int lc = 0;
    for (int r = threadIdx.x; r < Bn; r += 256) {
        int pz = pos_cnt[r];
        if (pz > 0 && pz < Bn - 1) {
            ls += row_sum[r] / (float)(Bn - 1);
            lc += 1;
        }
    }
    ssum[threadIdx.x] = ls;
    scnt[threadIdx.x] = lc;
    __syncthreads();
    for (int s = 128; s; s >>= 1) {
        if (threadIdx.x < s) {
            ssum[threadIdx.x] += ssum[threadIdx.x + s];
            scnt[threadIdx.x] += scnt[threadIdx.x + s];
        }
        __syncthreads();
    }
    if (threadIdx.x == 0) {
        float nv = fmaxf((float)scnt[0], 1.0f);
        out[0] = ssum[0] / nv;
    }
}

extern "C" void kernel_launch(void* const* d_in, const int* in_sizes, int n_in,
                              void* d_out, int out_size, void* d_ws, size_t ws_size,
                              hipStream_t stream) {
    const float* E = (const float*)d_in[0];   // [4096,512] f32
    const float* SF = (const float*)d_in[1];  // [4096,128] f32
    float* out = (float*)d_out;

    constexpr int NT = (Bn / 128) * (Bn / 128 + 1) / 2;  // 528 triangle tiles

    // ws: eh(4M) el(4M) fh(1M) fl(1M) row_sum(16K) pos_cnt(16K) rb_any(132B) posbits(1.06M)
    ushort* eh = (ushort*)d_ws;
    ushort* el = eh + (size_t)Bn * Dd;
    ushort* fh = el + (size_t)Bn * Dd;
    ushort* fl = fh + (size_t)Bn * Ff;
    float* row_sum = (float*)(fl + (size_t)Bn * Ff);
    int* pos_cnt = (int*)(row_sum + Bn);
    int* rb_any = pos_cnt + Bn;
    unsigned long long* posbits = (unsigned long long*)(((size_t)(rb_any + 64) + 15) & ~15ull);

    prep_kernel<<<Bn / 4, 256, 0, stream>>>(SF, fh, fl, row_sum, pos_cnt, rb_any);
    t_kernel<<<NT, 256, 0, stream>>>(fh, fl, posbits, pos_cnt);
    flags_kernel<<<Bn / 256, 256, 0, stream>>>(pos_cnt, rb_any);
    split_E_kernel<<<(Bn * Dd / 4) / 256, 256, 0, stream>>>(E, eh, el, rb_any);
    s_kernel<<<NT, 256, 0, stream>>>(eh, el, posbits, rb_any, row_sum);
    finalize_kernel<<<1, 256, 0, stream>>>(row_sum, pos_cnt, out);
}

// Round 7
// 83.026 us; speedup vs baseline: 1.2236x; 1.2236x over previous
//
#include <hip/hip_runtime.h>
#include <math.h>

// ContrastiveLoss round 7: margin-gated hh-only T pass (exact decisions),
// LDS-staged (validated), self-gated split_E/s_kernel (flags launch dropped).

constexpr int Bn = 4096;
constexpr int Dd = 512;
constexpr int Ff = 128;
constexpr float MARGIN = 0.015625f;  // |T_hh - T_3pass| < 2^-8; 4x safety

typedef __attribute__((ext_vector_type(8))) short bf16x8;
typedef __attribute__((ext_vector_type(4))) float f32x4;

__device__ __forceinline__ ushort f32_to_bf16(float x) {
    unsigned u = __float_as_uint(x);
    unsigned r = (u + 0x7FFFu + ((u >> 16) & 1u)) >> 16;  // RTNE
    return (ushort)r;
}
__device__ __forceinline__ float bf16_to_f32(ushort h) {
    return __uint_as_float(((unsigned)h) << 16);
}

// prep: L2-normalize + hi/lo split F (1 wave per row), zero accumulators.
__global__ __launch_bounds__(256) void prep_kernel(const float* __restrict__ sf,
                                                   ushort* __restrict__ fh,
                                                   ushort* __restrict__ fl,
                                                   float* __restrict__ row_sum,
                                                   int* __restrict__ pos_cnt) {
    int gid = blockIdx.x * 256 + threadIdx.x;
    if (gid < Bn) { row_sum[gid] = 0.0f; pos_cnt[gid] = 0; }

    int row = blockIdx.x * 4 + (threadIdx.x >> 6);
    int lane = threadIdx.x & 63;
    const float2 v = *reinterpret_cast<const float2*>(&sf[(size_t)row * Ff + lane * 2]);
    float ss = v.x * v.x + v.y * v.y;
    #pragma unroll
    for (int off = 32; off; off >>= 1) ss += __shfl_xor(ss, off, 64);
    float inv = 1.0f / fmaxf(sqrtf(ss), 1e-12f);
    float fx = v.x * inv, fy = v.y * inv;
    ushort hx = f32_to_bf16(fx), hy = f32_to_bf16(fy);
    ushort lx = f32_to_bf16(fx - bf16_to_f32(hx));
    ushort ly = f32_to_bf16(fy - bf16_to_f32(hy));
    ushort2 h; h.x = hx; h.y = hy;
    ushort2 l; l.x = lx; l.y = ly;
    *reinterpret_cast<ushort2*>(&fh[(size_t)row * Ff + lane * 2]) = h;
    *reinterpret_cast<ushort2*>(&fl[(size_t)row * Ff + lane * 2]) = l;
}

__device__ __forceinline__ void tri_decode(int p, int& bi, int& bj) {
    bi = (int)((sqrtf(8.0f * (float)p + 1.0f) - 1.0f) * 0.5f);
    while ((bi + 1) * (bi + 2) / 2 <= p) ++bi;
    while (bi * (bi + 1) / 2 > p) --bi;
    bj = p - bi * (bi + 1) / 2;
}

// Stage a 128x64 bf16 tile via global_load_lds w=16; source pre-swizzled
// (rule #21), reads apply same XOR. Validated rounds 1-2: 0 bank conflicts.
__device__ __forceinline__ void stage_tile(const ushort* __restrict__ src, int stride,
                                           int k0, char* tile, int wave, int lane) {
    #pragma unroll
    for (int q = 0; q < 4; ++q) {
        int boff = wave * 4096 + q * 1024 + lane * 16;
        int row = boff >> 7;
        int cb = (boff & 127) ^ ((row & 7) << 4);
        const ushort* g = src + (size_t)row * stride + k0 + (cb >> 1);
        __builtin_amdgcn_global_load_lds(
            (const __attribute__((address_space(1))) void*)g,
            (__attribute__((address_space(3))) void*)(tile + wave * 4096 + q * 1024),
            16, 0, 0);
    }
}

__device__ __forceinline__ void mfma_step(f32x4 (&acc)[4][4], const char* At, const char* Bt,
                                          int wrow, int wcol, int lane) {
    #pragma unroll
    for (int ks = 0; ks < 2; ++ks) {
        bf16x8 a[4], b[4];
        int koff = ks * 64 + ((lane >> 4) << 4);
        #pragma unroll
        for (int m = 0; m < 4; ++m) {
            int row = wrow + m * 16 + (lane & 15);
            a[m] = *reinterpret_cast<const bf16x8*>(At + row * 128 + (koff ^ ((row & 7) << 4)));
        }
        #pragma unroll
        for (int n = 0; n < 4; ++n) {
            int row = wcol + n * 16 + (lane & 15);
            b[n] = *reinterpret_cast<const bf16x8*>(Bt + row * 128 + (koff ^ ((row & 7) << 4)));
        }
        #pragma unroll
        for (int m = 0; m < 4; ++m)
            #pragma unroll
            for (int n = 0; n < 4; ++n)
                acc[m][n] = __builtin_amdgcn_mfma_f32_16x16x32_bf16(a[m], b[n], acc[m][n], 0, 0, 0);
    }
}

// T kernel: hh pass only; hl+lh correction only if a tile entry is within
// MARGIN of the threshold (provably preserves every decision; cold path).
__global__ __launch_bounds__(256) void t_kernel(const ushort* __restrict__ Fh,
                                                const ushort* __restrict__ Fl,
                                                unsigned long long* __restrict__ posbits,
                                                int* __restrict__ pos_cnt) {
    __shared__ __align__(16) char smem[32768];
    __shared__ int nf;
    char* At = smem;
    char* Bt = smem + 16384;

    int bi, bj; tri_decode(blockIdx.x, bi, bj);
    const int ti = bi * 128, tj = bj * 128;
    const int tid = threadIdx.x;
    const int lane = tid & 63;
    const int wave = tid >> 6;
    const int wrow = (wave >> 1) * 64;
    const int wcol = (wave & 1) * 64;

    if (tid == 0) nf = 0;

    f32x4 acc[4][4];
    const f32x4 z4 = {0.0f, 0.0f, 0.0f, 0.0f};
    #pragma unroll
    for (int m = 0; m < 4; ++m)
        #pragma unroll
        for (int n = 0; n < 4; ++n) acc[m][n] = z4;

    // hh pass, K = 128 in two 64-steps.
    for (int k0 = 0; k0 < Ff; k0 += 64) {
        stage_tile(Fh + (size_t)ti * Ff, Ff, k0, At, wave, lane);
        stage_tile(Fh + (size_t)tj * Ff, Ff, k0, Bt, wave, lane);
        __syncthreads();
        mfma_step(acc, At, Bt, wrow, wcol, lane);
        __syncthreads();
    }

    // Near-threshold detection (block-wide OR).
    bool nr = false;
    #pragma unroll
    for (int m = 0; m < 4; ++m)
        #pragma unroll
        for (int n = 0; n < 4; ++n)
            #pragma unroll
            for (int r = 0; r < 4; ++r)
                nr |= fabsf(acc[m][n][r] - 0.5f) < MARGIN;
    if (__any(nr)) { if (lane == 0) nf = 1; }
    __syncthreads();

    if (nf) {  // cold path: full 3-pass precision for this tile
        for (int k0 = 0; k0 < Ff; k0 += 64) {   // hl: fh(i) . fl(j)
            stage_tile(Fh + (size_t)ti * Ff, Ff, k0, At, wave, lane);
            stage_tile(Fl + (size_t)tj * Ff, Ff, k0, Bt, wave, lane);
            __syncthreads();
            mfma_step(acc, At, Bt, wrow, wcol, lane);
            __syncthreads();
        }
        for (int k0 = 0; k0 < Ff; k0 += 64) {   // lh: fl(i) . fh(j)
            stage_tile(Fl + (size_t)ti * Ff, Ff, k0, At, wave, lane);
            stage_tile(Fh + (size_t)tj * Ff, Ff, k0, Bt, wave, lane);
            __syncthreads();
            mfma_step(acc, At, Bt, wrow, wcol, lane);
            __syncthreads();
        }
    }

    // Positive bits (raw T > 0.5); per-tile cache for the S path.
    unsigned long long pm = 0;
    #pragma unroll
    for (int m = 0; m < 4; ++m)
        #pragma unroll
        for (int n = 0; n < 4; ++n)
            #pragma unroll
            for (int r = 0; r < 4; ++r)
                if (acc[m][n][r] > 0.5f) pm |= 1ull << (m * 16 + n * 4 + r);
    posbits[(size_t)blockIdx.x * 256 + tid] = pm;

    // Per-row positive counts (off-diag only), rows + mirrored cols.
    int colC[4] = {0, 0, 0, 0};
    #pragma unroll
    for (int m = 0; m < 4; ++m) {
        #pragma unroll
        for (int r = 0; r < 4; ++r) {
            int c = 0;
            int gi = ti + wrow + m * 16 + ((lane >> 4) << 2) + r;
            #pragma unroll
            for (int n = 0; n < 4; ++n) {
                int gj = tj + wcol + n * 16 + (lane & 15);
                bool pos = (pm >> (m * 16 + n * 4 + r)) & 1;
                if (gi != gj && pos) {
                    c += 1;
                    if (bi != bj) colC[n] += 1;
                }
            }
            #pragma unroll
            for (int off = 8; off; off >>= 1) c += __shfl_xor(c, off, 16);
            if ((lane & 15) == 0 && c) atomicAdd(&pos_cnt[gi], c);
        }
    }
    if (bi != bj) {
        #pragma unroll
        for (int n = 0; n < 4; ++n) {
            int c = colC[n];
            c += __shfl_xor(c, 16, 64);
            c += __shfl_xor(c, 32, 64);
            if ((lane >> 4) == 0 && c) {
                int gj = tj + wcol + n * 16 + (lane & 15);
                atomicAdd(&pos_cnt[gj], c);
            }
        }
    }
}

// split_E: self-gates by scanning pos_cnt (any valid row anywhere?).
// 512 blocks x 4 float4-iterations cover all of E.
__global__ __launch_bounds__(256) void split_E_kernel(const float* __restrict__ E,
                                                      ushort* __restrict__ eh,
                                                      ushort* __restrict__ el,
                                                      const int* __restrict__ pos_cnt) {
    __shared__ int go;
    if (threadIdx.x == 0) go = 0;
    __syncthreads();
    bool val = false;
    for (int r = threadIdx.x; r < Bn; r += 256) {
        int pc = pos_cnt[r];
        val |= (pc > 0) && (pc < Bn - 1);
    }
    if (__any(val)) { if ((threadIdx.x & 63) == 0) go = 1; }
    __syncthreads();
    if (!go) return;

    int base = blockIdx.x * 256 + threadIdx.x;
    #pragma unroll
    for (int it = 0; it < 4; ++it) {
        size_t i = ((size_t)base + (size_t)it * 131072) * 4;
        float4 v = *reinterpret_cast<const float4*>(&E[i]);
        float c[4] = {v.x, v.y, v.z, v.w};
        ushort4 h, l;
        ushort hu[4], lu[4];
        #pragma unroll
        for (int j = 0; j < 4; ++j) {
            hu[j] = f32_to_bf16(c[j]);
            lu[j] = f32_to_bf16(c[j] - bf16_to_f32(hu[j]));
        }
        h.x = hu[0]; h.y = hu[1]; h.z = hu[2]; h.w = hu[3];
        l.x = lu[0]; l.y = lu[1]; l.z = lu[2]; l.w = lu[3];
        *reinterpret_cast<ushort4*>(&eh[i]) = h;
        *reinterpret_cast<ushort4*>(&el[i]) = l;
    }
}

// S kernel: self-gates on its own 256 rows' pos_cnt; full 3-pass when active.
__global__ __launch_bounds__(256) void s_kernel(const ushort* __restrict__ Eh,
                                                const ushort* __restrict__ El,
                                                const unsigned long long* __restrict__ posbits,
                                                const int* __restrict__ pos_cnt,
                                                float* __restrict__ row_sum) {
    __shared__ __align__(16) char smem[65536];
    __shared__ int go;
    int bi, bj; tri_decode(blockIdx.x, bi, bj);
    const int ti = bi * 128, tj = bj * 128;
    const int tid = threadIdx.x;

    if (tid == 0) go = 0;
    __syncthreads();
    int pc = (tid < 128) ? pos_cnt[ti + tid] : pos_cnt[tj + tid - 128];
    bool val = (pc > 0) && (pc < Bn - 1);
    if (__any(val)) { if ((tid & 63) == 0) go = 1; }
    __syncthreads();
    if (!go) return;

    char* Ah = smem;
    char* Al = smem + 16384;
    char* Bh = smem + 32768;
    char* Bl = smem + 49152;

    const int lane = tid & 63;
    const int wave = tid >> 6;
    const int wrow = (wave >> 1) * 64;
    const int wcol = (wave & 1) * 64;

    f32x4 acc[4][4];
    const f32x4 z4 = {0.0f, 0.0f, 0.0f, 0.0f};
    #pragma unroll
    for (int m = 0; m < 4; ++m)
        #pragma unroll
        for (int n = 0; n < 4; ++n) acc[m][n] = z4;

    for (int k0 = 0; k0 < Dd; k0 += 64) {
        stage_tile(Eh + (size_t)ti * Dd, Dd, k0, Ah, wave, lane);
        stage_tile(El + (size_t)ti * Dd, Dd, k0, Al, wave, lane);
        stage_tile(Eh + (size_t)tj * Dd, Dd, k0, Bh, wave, lane);
        stage_tile(El + (size_t)tj * Dd, Dd, k0, Bl, wave, lane);
        __syncthreads();
        mfma_step(acc, Ah, Bh, wrow, wcol, lane);
        mfma_step(acc, Ah, Bl, wrow, wcol, lane);
        mfma_step(acc, Al, Bh, wrow, wcol, lane);
        __syncthreads();
    }

    unsigned long long pm = posbits[(size_t)blockIdx.x * 256 + tid];

    float colS[4] = {0, 0, 0, 0};
    #pragma unroll
    for (int m = 0; m < 4; ++m) {
        #pragma unroll
        for (int r = 0; r < 4; ++r) {
            float s = 0.0f;
            int gi = ti + wrow + m * 16 + ((lane >> 4) << 2) + r;
            #pragma unroll
            for (int n = 0; n < 4; ++n) {
                int gj = tj + wcol + n * 16 + (lane & 15);
                if (gi != gj) {
                    float S = acc[m][n][r] * 10.0f;
                    bool pos = (pm >> (m * 16 + n * 4 + r)) & 1;
                    float x = pos ? -S : S;
                    float sp = fmaxf(x, 0.0f) + log1pf(expf(-fabsf(x)));
                    s += sp;
                    if (bi != bj) colS[n] += sp;
                }
            }
            #pragma unroll
            for (int off = 8; off; off >>= 1) s += __shfl_xor(s, off, 16);
            if ((lane & 15) == 0) atomicAdd(&row_sum[gi], s);
        }
    }
    if (bi != bj) {
        #pragma unroll
        for (int n = 0; n < 4; ++n) {
            float s = colS[n];
            s += __shfl_xor(s, 16, 64);
            s += __shfl_xor(s, 32, 64);
            if ((lane >> 4) == 0) {
                int gj = tj + wcol + n * 16 + (lane & 15);
                atomicAdd(&row_sum[gj], s);
            }
        }
    }
}

__global__ __launch_bounds__(256) void finalize_kernel(const float* __restrict__ row_sum,
                                                       const int* __restrict__ pos_cnt,
                                                       float* __restrict__ out) {
    __shared__ float ssum[256];
    __shared__ int scnt[256];
    float ls = 0.0f;
    int lc = 0;
    for (int r = threadIdx.x; r < Bn; r += 256) {
        int pz = pos_cnt[r];
        if (pz > 0 && pz < Bn - 1) {
            ls += row_sum[r] / (float)(Bn - 1);
            lc += 1;
        }
    }
    ssum[threadIdx.x] = ls;
    scnt[threadIdx.x] = lc;
    __syncthreads();
    for (int s = 128; s; s >>= 1) {
        if (threadIdx.x < s) {
            ssum[threadIdx.x] += ssum[threadIdx.x + s];
            scnt[threadIdx.x] += scnt[threadIdx.x + s];
        }
        __syncthreads();
    }
    if (threadIdx.x == 0) {
        float nv = fmaxf((float)scnt[0], 1.0f);
        out[0] = ssum[0] / nv;
    }
}

extern "C" void kernel_launch(void* const* d_in, const int* in_sizes, int n_in,
                              void* d_out, int out_size, void* d_ws, size_t ws_size,
                              hipStream_t stream) {
    const float* E = (const float*)d_in[0];   // [4096,512] f32
    const float* SF = (const float*)d_in[1];  // [4096,128] f32
    float* out = (float*)d_out;

    constexpr int NT = (Bn / 128) * (Bn / 128 + 1) / 2;  // 528 triangle tiles

    // ws: eh(4M) el(4M) fh(1M) fl(1M) row_sum(16K) pos_cnt(16K) posbits(1.08M)
    ushort* eh = (ushort*)d_ws;
    ushort* el = eh + (size_t)Bn * Dd;
    ushort* fh = el + (size_t)Bn * Dd;
    ushort* fl = fh + (size_t)Bn * Ff;
    float* row_sum = (float*)(fl + (size_t)Bn * Ff);
    int* pos_cnt = (int*)(row_sum + Bn);
    unsigned long long* posbits = (unsigned long long*)(((size_t)(pos_cnt + Bn) + 15) & ~15ull);

    prep_kernel<<<Bn / 4, 256, 0, stream>>>(SF, fh, fl, row_sum, pos_cnt);
    t_kernel<<<NT, 256, 0, stream>>>(fh, fl, posbits, pos_cnt);
    split_E_kernel<<<512, 256, 0, stream>>>(E, eh, el, pos_cnt);
    s_kernel<<<NT, 256, 0, stream>>>(eh, el, posbits, pos_cnt, row_sum);
    finalize_kernel<<<1, 256, 0, stream>>>(row_sum, pos_cnt, out);
}